// Round 7
// baseline (79.537 us; speedup 1.0000x reference)
//
#include <hip/hip_runtime.h>
#include <math.h>

#define H 1024
#define S 20
#define V 50257
#define NGRP ((V + 3) / 4)        // 12565 row-groups of 4
#define KC_BLOCKS 512
#define KC_WAVES (KC_BLOCKS * 8)  // 4096 waves
#define MAGIC 0x1ACFFC1Du

__device__ __forceinline__ float wave_reduce_sum(float v) {
  #pragma unroll
  for (int off = 32; off > 0; off >>= 1)
    v += __shfl_xor(v, off, 64);
  return v;
}

// ============ kA: independent streaming work (32 MB) ============
// b in [0,256):    attention energy -> bpart[S][256]
// b in [256,1024): gie[W] = dot(w_ih[W][0:H], embed) + b_ih[W]
// b in [1024,1792): ghv[W] = dot(w_hh[W], hidden) + b_hh[W]
__global__ __launch_bounds__(256) void kA(
    const int* __restrict__ token,
    const float* __restrict__ hidden,
    const float* __restrict__ enc,
    const float* __restrict__ embed_table,
    const float* __restrict__ attn_w,
    const float* __restrict__ attn_b,
    const float* __restrict__ v_w,
    const float* __restrict__ w_ih,
    const float* __restrict__ w_hh,
    const float* __restrict__ b_ih,
    const float* __restrict__ b_hh,
    float* __restrict__ bpart,   // [S][256]
    float* __restrict__ gie,     // [3H]
    float* __restrict__ ghv)     // [3H]
{
  __shared__ float esh[4][S];
  const int t = threadIdx.x;
  const int lane = t & 63;
  const int wv = t >> 6;
  const int b = blockIdx.x;

  if (b < 256) {
    const int j = b * 4 + wv;
    const float* wrow = attn_w + (size_t)j * (2 * H);
    float4 wlo[4], whi[4], hid4[4];
    #pragma unroll
    for (int q = 0; q < 4; ++q) {
      const int idx = lane + 64 * q;
      wlo[q]  = ((const float4*)wrow)[idx];
      whi[q]  = ((const float4*)(wrow + H))[idx];
      hid4[q] = ((const float4*)hidden)[idx];
    }
    float hp = 0.f;
    #pragma unroll
    for (int q = 0; q < 4; ++q)
      hp += wlo[q].x * hid4[q].x + wlo[q].y * hid4[q].y +
            wlo[q].z * hid4[q].z + wlo[q].w * hid4[q].w;
    hp = wave_reduce_sum(hp);

    float myval = 0.f;
    #pragma unroll
    for (int s = 0; s < S; ++s) {
      const float4* e4 = (const float4*)(enc + s * H);
      float es = 0.f;
      #pragma unroll
      for (int q = 0; q < 4; ++q) {
        const int idx = lane + 64 * q;
        const float4 e = e4[idx];
        es += whi[q].x * e.x + whi[q].y * e.y + whi[q].z * e.z + whi[q].w * e.w;
      }
      es = wave_reduce_sum(es);
      if (lane == s) myval = es;
    }
    if (lane < S)
      esh[wv][lane] = tanhf(hp + myval + attn_b[j]) * v_w[j];
    __syncthreads();
    if (wv == 0 && lane < S)
      bpart[lane * 256 + b] =
          esh[0][lane] + esh[1][lane] + esh[2][lane] + esh[3][lane];
  } else if (b < 1024) {
    const int W = (b - 256) * 4 + wv;
    const float* wr = w_ih + (size_t)W * (2 * H);
    const float* embed = embed_table + (size_t)(*token) * H;
    float a = 0.f;
    #pragma unroll
    for (int q = 0; q < 4; ++q) {
      const int idx = lane + 64 * q;
      const float4 w = ((const float4*)wr)[idx];
      const float4 e = ((const float4*)embed)[idx];
      a += w.x * e.x + w.y * e.y + w.z * e.z + w.w * e.w;
    }
    a = wave_reduce_sum(a);
    if (lane == 0) gie[W] = a + b_ih[W];
  } else {
    const int W = (b - 1024) * 4 + wv;
    const float* wr = w_hh + (size_t)W * H;
    float a = 0.f;
    #pragma unroll
    for (int q = 0; q < 4; ++q) {
      const int idx = lane + 64 * q;
      const float4 w = ((const float4*)wr)[idx];
      const float4 h = ((const float4*)hidden)[idx];
      a += w.x * h.x + w.y * h.y + w.z * h.z + w.w * h.w;
    }
    a = wave_reduce_sum(a);
    if (lane == 0) ghv[W] = a + b_hh[W];
  }
}

// ============ kCf: produce 2 hnew/block -> flag -> poll -> stream logits =====
// 512 blocks x 512 threads, 2 blocks/CU co-resident (launch_bounds(512,4)).
__global__ __launch_bounds__(512, 4) void kCf(
    const float* __restrict__ enc,
    const float* __restrict__ bpart,     // [S][256]
    const float* __restrict__ w_ih,
    const float* __restrict__ gie,       // [3H]
    const float* __restrict__ ghv,       // [3H]
    const float* __restrict__ hidden,
    const float* __restrict__ out_w,     // [V][H]
    const float* __restrict__ out_b,     // [V]
    float* __restrict__ out,             // [V + H]
    float* __restrict__ hnew,            // [H] (agent-scope mailbox)
    unsigned* __restrict__ flags,        // [KC_BLOCKS]
    float* __restrict__ pmax,
    float* __restrict__ psum)
{
  __shared__ float scores_sh[S];
  __shared__ float attn_sh[S];
  __shared__ float wsh[H];
  __shared__ float gred[8];
  __shared__ float stat_m[8];
  __shared__ float stat_s[8];
  const int t = threadIdx.x;
  const int lane = t & 63;
  const int wv = t >> 6;
  const int b = blockIdx.x;

  // ---- producer: hnew[2b], hnew[2b+1] ----
  for (int s = wv; s < S; s += 8) {
    const float4 p = ((const float4*)(bpart + s * 256))[lane];
    float v = wave_reduce_sum(p.x + p.y + p.z + p.w);
    if (lane == 0) scores_sh[s] = v;
  }
  __syncthreads();
  if (t == 0) {
    float m = -1e30f;
    for (int s = 0; s < S; ++s) m = fmaxf(m, scores_sh[s]);
    float sum = 0.f;
    for (int s = 0; s < S; ++s) {
      const float e = expf(scores_sh[s] - m);
      attn_sh[s] = e;
      sum += e;
    }
    const float inv = 1.f / sum;
    for (int s = 0; s < S; ++s) attn_sh[s] *= inv;
  }
  __syncthreads();
  #pragma unroll
  for (int r = 0; r < 2; ++r) {
    const int h = t + r * 512;
    float acc = 0.f;
    #pragma unroll
    for (int s = 0; s < S; ++s) acc += attn_sh[s] * enc[s * H + h];
    wsh[h] = acc;
  }
  __syncthreads();

  if (wv < 6) {
    const int g = wv >> 1, jj = wv & 1;
    const int j = 2 * b + jj;
    const float* wr = w_ih + (size_t)(g * H + j) * (2 * H) + H;
    float a = 0.f;
    #pragma unroll
    for (int q = 0; q < 4; ++q) {
      const int idx = lane + 64 * q;
      const float4 w = ((const float4*)wr)[idx];
      const float4 c = ((const float4*)wsh)[idx];
      a += w.x * c.x + w.y * c.y + w.z * c.z + w.w * c.w;
    }
    a = wave_reduce_sum(a);
    if (lane == 0) gred[wv] = a;
  }
  __syncthreads();
  if (t == 0) {
    #pragma unroll
    for (int jj = 0; jj < 2; ++jj) {
      const int j = 2 * b + jj;
      const float i_r = gie[j]         + gred[0 + jj];
      const float i_z = gie[H + j]     + gred[2 + jj];
      const float i_n = gie[2 * H + j] + gred[4 + jj];
      const float h_r = ghv[j];
      const float h_z = ghv[H + j];
      const float h_n = ghv[2 * H + j];
      const float r = 1.f / (1.f + expf(-(i_r + h_r)));
      const float z = 1.f / (1.f + expf(-(i_z + h_z)));
      const float n = tanhf(i_n + r * h_n);
      const float hn = (1.f - z) * n + z * hidden[j];
      __hip_atomic_store(&hnew[j], hn, __ATOMIC_RELAXED, __HIP_MEMORY_SCOPE_AGENT);
      out[V + j] = hn;
    }
    __hip_atomic_store(&flags[b], MAGIC, __ATOMIC_RELEASE, __HIP_MEMORY_SCOPE_AGENT);
  }

  // ---- poll all flags (one-directional wait; each wave independently) ----
  for (;;) {
    unsigned ok = 1u;
    #pragma unroll
    for (int r = 0; r < 8; ++r) {
      const unsigned f = __hip_atomic_load(&flags[lane + 64 * r],
                                           __ATOMIC_RELAXED, __HIP_MEMORY_SCOPE_AGENT);
      ok &= (f == MAGIC) ? 1u : 0u;
    }
    if (__all((int)ok)) break;
    __builtin_amdgcn_s_sleep(4);
  }

  // ---- load hnew fragment (agent-scope, coherent) ----
  float4 h4[4];
  #pragma unroll
  for (int q = 0; q < 4; ++q) {
    const int base = 4 * (lane + 64 * q);
    h4[q].x = __hip_atomic_load(&hnew[base + 0], __ATOMIC_RELAXED, __HIP_MEMORY_SCOPE_AGENT);
    h4[q].y = __hip_atomic_load(&hnew[base + 1], __ATOMIC_RELAXED, __HIP_MEMORY_SCOPE_AGENT);
    h4[q].z = __hip_atomic_load(&hnew[base + 2], __ATOMIC_RELAXED, __HIP_MEMORY_SCOPE_AGENT);
    h4[q].w = __hip_atomic_load(&hnew[base + 3], __ATOMIC_RELAXED, __HIP_MEMORY_SCOPE_AGENT);
  }

  // ---- streaming logits, grid-stride, 4 rows/wave ----
  const int gw = b * 8 + wv;
  float wm = -INFINITY, wsum = 0.f;

  for (int grp = gw; grp < NGRP; grp += KC_WAVES) {
    const int vbase = grp * 4;
    const int v0 = vbase;
    const int v1 = (vbase + 1 < V) ? vbase + 1 : (V - 1);
    const int v2 = (vbase + 2 < V) ? vbase + 2 : (V - 1);
    const int v3 = (vbase + 3 < V) ? vbase + 3 : (V - 1);
    const float4* r0 = (const float4*)(out_w + (size_t)v0 * H);
    const float4* r1 = (const float4*)(out_w + (size_t)v1 * H);
    const float4* r2 = (const float4*)(out_w + (size_t)v2 * H);
    const float4* r3 = (const float4*)(out_w + (size_t)v3 * H);
    float a0 = 0.f, a1 = 0.f, a2 = 0.f, a3 = 0.f;
    #pragma unroll
    for (int q = 0; q < 4; ++q) {
      const int idx = lane + 64 * q;
      const float4 w0 = r0[idx];
      const float4 w1 = r1[idx];
      const float4 w2 = r2[idx];
      const float4 w3 = r3[idx];
      a0 += w0.x * h4[q].x + w0.y * h4[q].y + w0.z * h4[q].z + w0.w * h4[q].w;
      a1 += w1.x * h4[q].x + w1.y * h4[q].y + w1.z * h4[q].z + w1.w * h4[q].w;
      a2 += w2.x * h4[q].x + w2.y * h4[q].y + w2.z * h4[q].z + w2.w * h4[q].w;
      a3 += w3.x * h4[q].x + w3.y * h4[q].y + w3.z * h4[q].z + w3.w * h4[q].w;
    }
    a0 = wave_reduce_sum(a0);
    a1 = wave_reduce_sum(a1);
    a2 = wave_reduce_sum(a2);
    a3 = wave_reduce_sum(a3);
    const float val0 = a0 + out_b[v0];
    const float val1 = (vbase + 1 < V) ? a1 + out_b[v1] : -INFINITY;
    const float val2 = (vbase + 2 < V) ? a2 + out_b[v2] : -INFINITY;
    const float val3 = (vbase + 3 < V) ? a3 + out_b[v3] : -INFINITY;

    if (lane == 0) {
      if (vbase + 3 < V) {
        float4 o; o.x = val0; o.y = val1; o.z = val2; o.w = val3;
        *reinterpret_cast<float4*>(out + vbase) = o;
      } else {
        out[vbase] = val0;
        if (vbase + 1 < V) out[vbase + 1] = val1;
        if (vbase + 2 < V) out[vbase + 2] = val2;
      }
    }

    const float gm = fmaxf(fmaxf(val0, val1), fmaxf(val2, val3));
    const float M2 = fmaxf(wm, gm);
    wsum = wsum * expf(wm - M2) +
           expf(val0 - M2) + expf(val1 - M2) + expf(val2 - M2) + expf(val3 - M2);
    wm = M2;
  }

  if (lane == 0) { stat_m[wv] = wm; stat_s[wv] = wsum; }
  __syncthreads();
  if (t == 0) {
    float M = stat_m[0], Ss = stat_s[0];
    #pragma unroll
    for (int i = 1; i < 8; ++i) {
      const float m2 = stat_m[i], s2 = stat_s[i];
      const float M2 = fmaxf(M, m2);
      Ss = Ss * expf(M - M2) + s2 * expf(m2 - M2);
      M = M2;
    }
    pmax[b] = M;
    psum[b] = Ss;
  }
}

// ============ kD: block-redundant stat reduce + subtract ============
// ceil(V/512) blocks x 512; thread t owns stat pair t (all finite).
__global__ __launch_bounds__(512) void kD(
    const float* __restrict__ pmax,
    const float* __restrict__ psum,
    float* __restrict__ out)
{
  __shared__ float sm[8];
  __shared__ float ss[8];
  __shared__ float Tsh;
  const int t = threadIdx.x, lane = t & 63, wv = t >> 6;

  float dm = pmax[t];
  float dsv = psum[t];
  #pragma unroll
  for (int off = 32; off > 0; off >>= 1) {
    const float m2 = __shfl_xor(dm, off, 64);
    const float s2 = __shfl_xor(dsv, off, 64);
    const float M2 = fmaxf(dm, m2);
    dsv = dsv * expf(dm - M2) + s2 * expf(m2 - M2);
    dm = M2;
  }
  if (lane == 0) { sm[wv] = dm; ss[wv] = dsv; }
  __syncthreads();
  if (t == 0) {
    float M = sm[0], Ss = ss[0];
    #pragma unroll
    for (int i = 1; i < 8; ++i) {
      const float m2 = sm[i], s2 = ss[i];
      const float M2 = fmaxf(M, m2);
      Ss = Ss * expf(M - M2) + s2 * expf(m2 - M2);
      M = M2;
    }
    Tsh = M + logf(Ss);
  }
  __syncthreads();
  const float T = Tsh;
  const int i = blockIdx.x * 512 + t;
  if (i < V) out[i] -= T;
}

extern "C" void kernel_launch(void* const* d_in, const int* in_sizes, int n_in,
                              void* d_out, int out_size, void* d_ws, size_t ws_size,
                              hipStream_t stream) {
  const int*   token       = (const int*)d_in[0];
  const float* hidden      = (const float*)d_in[1];
  const float* enc         = (const float*)d_in[2];
  const float* embed_table = (const float*)d_in[3];
  const float* attn_w      = (const float*)d_in[4];
  const float* attn_b      = (const float*)d_in[5];
  const float* v_w         = (const float*)d_in[6];
  const float* w_ih        = (const float*)d_in[7];
  const float* w_hh        = (const float*)d_in[8];
  const float* b_ih        = (const float*)d_in[9];
  const float* b_hh        = (const float*)d_in[10];
  const float* out_w       = (const float*)d_in[11];
  const float* out_b       = (const float*)d_in[12];
  float* out = (float*)d_out;
  float* ws  = (float*)d_ws;

  // ws layout (floats)
  float*    bpart = ws;            // 5120
  float*    gie   = ws + 5120;     // 3072
  float*    ghv   = ws + 8192;     // 3072
  float*    hnew  = ws + 11264;    // 1024
  float*    pmax  = ws + 12288;    // 512
  float*    psum  = ws + 12800;    // 512
  unsigned* flags = (unsigned*)(ws + 13312);  // 512

  kA<<<1792, 256, 0, stream>>>(token, hidden, enc, embed_table, attn_w, attn_b,
                               v_w, w_ih, w_hh, b_ih, b_hh, bpart, gie, ghv);
  kCf<<<KC_BLOCKS, 512, 0, stream>>>(enc, bpart, w_ih, gie, ghv, hidden,
                                     out_w, out_b, out, hnew, flags, pmax, psum);
  kD<<<(V + 511) / 512, 512, 0, stream>>>(pmax, psum, out);
}

// Round 8
// 64.751 us; speedup vs baseline: 1.2284x; 1.2284x over previous
//
#include <hip/hip_runtime.h>
#include <math.h>

#define H 1024
#define S 20
#define V 50257
#define NGRP ((V + 3) / 4)        // 12565 row-groups of 4
#define KC_BLOCKS 512
#define KC_WAVES (KC_BLOCKS * 8)  // 4096 waves

__device__ __forceinline__ float wave_reduce_sum(float v) {
  #pragma unroll
  for (int off = 32; off > 0; off >>= 1)
    v += __shfl_xor(v, off, 64);
  return v;
}

// ============ kA: ALL softmax-independent streaming (44 MB) ============
// b in [0,256):     attention energy -> bpart[S][256]
// b in [256,1024):  gie[W] = dot(w_ih[W][0:H], embed) + b_ih[W]
// b in [1024,1792): E[s][W] = dot(w_ih[W][H:2H], enc[s])  (s=0..19)
// b in [1792,2560): ghv[W] = dot(w_hh[W], hidden) + b_hh[W]
__global__ __launch_bounds__(256) void kA(
    const int* __restrict__ token,
    const float* __restrict__ hidden,
    const float* __restrict__ enc,
    const float* __restrict__ embed_table,
    const float* __restrict__ attn_w,
    const float* __restrict__ attn_b,
    const float* __restrict__ v_w,
    const float* __restrict__ w_ih,
    const float* __restrict__ w_hh,
    const float* __restrict__ b_ih,
    const float* __restrict__ b_hh,
    float* __restrict__ bpart,   // [S][256]
    float* __restrict__ gie,     // [3H]
    float* __restrict__ Emat,    // [S][3H]
    float* __restrict__ ghv)     // [3H]
{
  __shared__ float esh[4][S];
  const int t = threadIdx.x;
  const int lane = t & 63;
  const int wv = t >> 6;
  const int b = blockIdx.x;

  if (b < 256) {
    const int j = b * 4 + wv;
    const float* wrow = attn_w + (size_t)j * (2 * H);
    float4 wlo[4], whi[4], hid4[4];
    #pragma unroll
    for (int q = 0; q < 4; ++q) {
      const int idx = lane + 64 * q;
      wlo[q]  = ((const float4*)wrow)[idx];
      whi[q]  = ((const float4*)(wrow + H))[idx];
      hid4[q] = ((const float4*)hidden)[idx];
    }
    float hp = 0.f;
    #pragma unroll
    for (int q = 0; q < 4; ++q)
      hp += wlo[q].x * hid4[q].x + wlo[q].y * hid4[q].y +
            wlo[q].z * hid4[q].z + wlo[q].w * hid4[q].w;
    hp = wave_reduce_sum(hp);

    float myval = 0.f;
    #pragma unroll
    for (int s = 0; s < S; ++s) {
      const float4* e4 = (const float4*)(enc + s * H);
      float es = 0.f;
      #pragma unroll
      for (int q = 0; q < 4; ++q) {
        const float4 e = e4[lane + 64 * q];
        es += whi[q].x * e.x + whi[q].y * e.y + whi[q].z * e.z + whi[q].w * e.w;
      }
      es = wave_reduce_sum(es);
      if (lane == s) myval = es;
    }
    if (lane < S)
      esh[wv][lane] = tanhf(hp + myval + attn_b[j]) * v_w[j];
    __syncthreads();
    if (wv == 0 && lane < S)
      bpart[lane * 256 + b] =
          esh[0][lane] + esh[1][lane] + esh[2][lane] + esh[3][lane];
  } else if (b < 1024) {
    const int W = (b - 256) * 4 + wv;
    const float* wr = w_ih + (size_t)W * (2 * H);
    const float* embed = embed_table + (size_t)(*token) * H;
    float a = 0.f;
    #pragma unroll
    for (int q = 0; q < 4; ++q) {
      const int idx = lane + 64 * q;
      const float4 w = ((const float4*)wr)[idx];
      const float4 e = ((const float4*)embed)[idx];
      a += w.x * e.x + w.y * e.y + w.z * e.z + w.w * e.w;
    }
    a = wave_reduce_sum(a);
    if (lane == 0) gie[W] = a + b_ih[W];
  } else if (b < 1792) {
    const int W = (b - 1024) * 4 + wv;
    const float* wr = w_ih + (size_t)W * (2 * H) + H;
    float4 wv4[4];
    #pragma unroll
    for (int q = 0; q < 4; ++q) wv4[q] = ((const float4*)wr)[lane + 64 * q];
    float myE = 0.f;
    #pragma unroll
    for (int s = 0; s < S; ++s) {
      const float4* e4 = (const float4*)(enc + s * H);
      float es = 0.f;
      #pragma unroll
      for (int q = 0; q < 4; ++q) {
        const float4 e = e4[lane + 64 * q];
        es += wv4[q].x * e.x + wv4[q].y * e.y + wv4[q].z * e.z + wv4[q].w * e.w;
      }
      es = wave_reduce_sum(es);
      if (lane == s) myE = es;
    }
    if (lane < S) Emat[lane * (3 * H) + W] = myE;
  } else {
    const int W = (b - 1792) * 4 + wv;
    const float* wr = w_hh + (size_t)W * H;
    float a = 0.f;
    #pragma unroll
    for (int q = 0; q < 4; ++q) {
      const int idx = lane + 64 * q;
      const float4 w = ((const float4*)wr)[idx];
      const float4 h = ((const float4*)hidden)[idx];
      a += w.x * h.x + w.y * h.y + w.z * h.z + w.w * h.w;
    }
    a = wave_reduce_sum(a);
    if (lane == 0) ghv[W] = a + b_hh[W];
  }
}

// ============ kC': redundant prologue (softmax+gates -> hnew in LDS),
//               then persistent grid-stride logits + per-block stats ==========
// 512 blocks x 512 threads. No cross-block communication anywhere.
__global__ __launch_bounds__(512) void kC(
    const float* __restrict__ bpart,    // [S][256]
    const float* __restrict__ gie,      // [3H]
    const float* __restrict__ Emat,     // [S][3H]
    const float* __restrict__ ghv,      // [3H]
    const float* __restrict__ hidden,   // [H]
    const float* __restrict__ out_w,    // [V][H]
    const float* __restrict__ out_b,    // [V]
    float* __restrict__ out,            // [V + H]
    float* __restrict__ pmax,           // [KC_BLOCKS]
    float* __restrict__ psum)           // [KC_BLOCKS]
{
  __shared__ float scores_sh[S];
  __shared__ float attn_sh[S];
  __shared__ float hnew_lds[H];
  __shared__ float stat_m[8];
  __shared__ float stat_s[8];
  const int t = threadIdx.x;
  const int lane = t & 63;
  const int wv = t >> 6;
  const int b = blockIdx.x;

  // ---- prologue: scores -> softmax ----
  for (int s = wv; s < S; s += 8) {
    const float4 p = ((const float4*)(bpart + s * 256))[lane];
    float v = wave_reduce_sum(p.x + p.y + p.z + p.w);
    if (lane == 0) scores_sh[s] = v;
  }
  __syncthreads();
  if (t == 0) {
    float m = -1e30f;
    for (int s = 0; s < S; ++s) m = fmaxf(m, scores_sh[s]);
    float sum = 0.f;
    for (int s = 0; s < S; ++s) {
      const float e = expf(scores_sh[s] - m);
      attn_sh[s] = e;
      sum += e;
    }
    const float inv = 1.f / sum;
    for (int s = 0; s < S; ++s) attn_sh[s] *= inv;
  }
  __syncthreads();

  // ---- prologue: gates -> hnew (each thread owns j = t and t+512) ----
  #pragma unroll
  for (int r = 0; r < 2; ++r) {
    const int j = t + r * 512;
    float g0 = 0.f, g1 = 0.f, g2 = 0.f;
    #pragma unroll
    for (int s = 0; s < S; ++s) {
      const float a = attn_sh[s];
      const float* Es = Emat + s * (3 * H);
      g0 += a * Es[j];
      g1 += a * Es[H + j];
      g2 += a * Es[2 * H + j];
    }
    const float i_r = gie[j]         + g0;
    const float i_z = gie[H + j]     + g1;
    const float i_n = gie[2 * H + j] + g2;
    const float h_r = ghv[j];
    const float h_z = ghv[H + j];
    const float h_n = ghv[2 * H + j];
    const float rr = 1.f / (1.f + expf(-(i_r + h_r)));
    const float zz = 1.f / (1.f + expf(-(i_z + h_z)));
    const float nn = tanhf(i_n + rr * h_n);
    const float hn = (1.f - zz) * nn + zz * hidden[j];
    hnew_lds[j] = hn;
    if (b == 0) out[V + j] = hn;
  }
  __syncthreads();

  float4 h4[4];
  #pragma unroll
  for (int q = 0; q < 4; ++q)
    h4[q] = ((const float4*)hnew_lds)[lane + 64 * q];

  // ---- streaming logits, grid-stride, 4 rows/wave ----
  const int gw = b * 8 + wv;
  float wm = -INFINITY, wsum = 0.f;

  for (int grp = gw; grp < NGRP; grp += KC_WAVES) {
    const int vbase = grp * 4;
    const int v0 = vbase;
    const int v1 = (vbase + 1 < V) ? vbase + 1 : (V - 1);
    const int v2 = (vbase + 2 < V) ? vbase + 2 : (V - 1);
    const int v3 = (vbase + 3 < V) ? vbase + 3 : (V - 1);
    const float4* r0 = (const float4*)(out_w + (size_t)v0 * H);
    const float4* r1 = (const float4*)(out_w + (size_t)v1 * H);
    const float4* r2 = (const float4*)(out_w + (size_t)v2 * H);
    const float4* r3 = (const float4*)(out_w + (size_t)v3 * H);
    float a0 = 0.f, a1 = 0.f, a2 = 0.f, a3 = 0.f;
    #pragma unroll
    for (int q = 0; q < 4; ++q) {
      const int idx = lane + 64 * q;
      const float4 w0 = r0[idx];
      const float4 w1 = r1[idx];
      const float4 w2 = r2[idx];
      const float4 w3 = r3[idx];
      a0 += w0.x * h4[q].x + w0.y * h4[q].y + w0.z * h4[q].z + w0.w * h4[q].w;
      a1 += w1.x * h4[q].x + w1.y * h4[q].y + w1.z * h4[q].z + w1.w * h4[q].w;
      a2 += w2.x * h4[q].x + w2.y * h4[q].y + w2.z * h4[q].z + w2.w * h4[q].w;
      a3 += w3.x * h4[q].x + w3.y * h4[q].y + w3.z * h4[q].z + w3.w * h4[q].w;
    }
    a0 = wave_reduce_sum(a0);
    a1 = wave_reduce_sum(a1);
    a2 = wave_reduce_sum(a2);
    a3 = wave_reduce_sum(a3);
    const float val0 = a0 + out_b[v0];
    const float val1 = (vbase + 1 < V) ? a1 + out_b[v1] : -INFINITY;
    const float val2 = (vbase + 2 < V) ? a2 + out_b[v2] : -INFINITY;
    const float val3 = (vbase + 3 < V) ? a3 + out_b[v3] : -INFINITY;

    if (lane == 0) {
      if (vbase + 3 < V) {
        float4 o; o.x = val0; o.y = val1; o.z = val2; o.w = val3;
        *reinterpret_cast<float4*>(out + vbase) = o;
      } else {
        out[vbase] = val0;
        if (vbase + 1 < V) out[vbase + 1] = val1;
        if (vbase + 2 < V) out[vbase + 2] = val2;
      }
    }

    const float gm = fmaxf(fmaxf(val0, val1), fmaxf(val2, val3));
    const float M2 = fmaxf(wm, gm);
    wsum = wsum * expf(wm - M2) +
           expf(val0 - M2) + expf(val1 - M2) + expf(val2 - M2) + expf(val3 - M2);
    wm = M2;
  }

  if (lane == 0) { stat_m[wv] = wm; stat_s[wv] = wsum; }
  __syncthreads();
  if (t == 0) {
    float M = stat_m[0], Ss = stat_s[0];
    #pragma unroll
    for (int i = 1; i < 8; ++i) {
      const float m2 = stat_m[i], s2 = stat_s[i];
      const float M2 = fmaxf(M, m2);
      Ss = Ss * expf(M - M2) + s2 * expf(m2 - M2);
      M = M2;
    }
    pmax[b] = M;
    psum[b] = Ss;
  }
}

// ============ kD: block-redundant stat reduce + subtract ============
// ceil(V/512) blocks x 512; thread t owns stat pair t (all finite).
__global__ __launch_bounds__(512) void kD(
    const float* __restrict__ pmax,
    const float* __restrict__ psum,
    float* __restrict__ out)
{
  __shared__ float sm[8];
  __shared__ float ss[8];
  __shared__ float Tsh;
  const int t = threadIdx.x, lane = t & 63, wv = t >> 6;

  float dm = pmax[t];
  float dsv = psum[t];
  #pragma unroll
  for (int off = 32; off > 0; off >>= 1) {
    const float m2 = __shfl_xor(dm, off, 64);
    const float s2 = __shfl_xor(dsv, off, 64);
    const float M2 = fmaxf(dm, m2);
    dsv = dsv * expf(dm - M2) + s2 * expf(m2 - M2);
    dm = M2;
  }
  if (lane == 0) { sm[wv] = dm; ss[wv] = dsv; }
  __syncthreads();
  if (t == 0) {
    float M = sm[0], Ss = ss[0];
    #pragma unroll
    for (int i = 1; i < 8; ++i) {
      const float m2 = sm[i], s2 = ss[i];
      const float M2 = fmaxf(M, m2);
      Ss = Ss * expf(M - M2) + s2 * expf(m2 - M2);
      M = M2;
    }
    Tsh = M + logf(Ss);
  }
  __syncthreads();
  const float T = Tsh;
  const int i = blockIdx.x * 512 + t;
  if (i < V) out[i] -= T;
}

extern "C" void kernel_launch(void* const* d_in, const int* in_sizes, int n_in,
                              void* d_out, int out_size, void* d_ws, size_t ws_size,
                              hipStream_t stream) {
  const int*   token       = (const int*)d_in[0];
  const float* hidden      = (const float*)d_in[1];
  const float* enc         = (const float*)d_in[2];
  const float* embed_table = (const float*)d_in[3];
  const float* attn_w      = (const float*)d_in[4];
  const float* attn_b      = (const float*)d_in[5];
  const float* v_w         = (const float*)d_in[6];
  const float* w_ih        = (const float*)d_in[7];
  const float* w_hh        = (const float*)d_in[8];
  const float* b_ih        = (const float*)d_in[9];
  const float* b_hh        = (const float*)d_in[10];
  const float* out_w       = (const float*)d_in[11];
  const float* out_b       = (const float*)d_in[12];
  float* out = (float*)d_out;
  float* ws  = (float*)d_ws;

  // ws layout (floats)
  float* bpart = ws;            // 5120
  float* gie   = ws + 5120;     // 3072
  float* ghv   = ws + 8192;     // 3072
  float* Emat  = ws + 11264;    // S*3H = 61440
  float* pmax  = ws + 72704;    // 512
  float* psum  = ws + 73216;    // 512

  kA<<<2560, 256, 0, stream>>>(token, hidden, enc, embed_table, attn_w, attn_b,
                               v_w, w_ih, w_hh, b_ih, b_hh, bpart, gie, Emat, ghv);
  kC<<<KC_BLOCKS, 512, 0, stream>>>(bpart, gie, Emat, ghv, hidden,
                                    out_w, out_b, out, pmax, psum);
  kD<<<(V + 511) / 512, 512, 0, stream>>>(pmax, psum, out);
}

// Round 9
// 60.297 us; speedup vs baseline: 1.3191x; 1.0739x over previous
//
#include <hip/hip_runtime.h>
#include <math.h>

#define H 1024
#define S 20
#define V 50257
#define KC_BLOCKS 512
#define KC_WAVES (KC_BLOCKS * 8)  // 4096 waves

__device__ __forceinline__ float wave_reduce_sum(float v) {
  #pragma unroll
  for (int off = 32; off > 0; off >>= 1)
    v += __shfl_xor(v, off, 64);
  return v;
}

// ============ kA: independent streaming work (32 MB) ============
// b in [0,256):    attention energy -> bpart[S][256]
// b in [256,1024): gie[W] = dot(w_ih[W][0:H], embed) + b_ih[W]
// b in [1024,1792): ghv[W] = dot(w_hh[W], hidden) + b_hh[W]
__global__ __launch_bounds__(256) void kA(
    const int* __restrict__ token,
    const float* __restrict__ hidden,
    const float* __restrict__ enc,
    const float* __restrict__ embed_table,
    const float* __restrict__ attn_w,
    const float* __restrict__ attn_b,
    const float* __restrict__ v_w,
    const float* __restrict__ w_ih,
    const float* __restrict__ w_hh,
    const float* __restrict__ b_ih,
    const float* __restrict__ b_hh,
    float* __restrict__ bpart,   // [S][256]
    float* __restrict__ gie,     // [3H]
    float* __restrict__ ghv)     // [3H]
{
  __shared__ float esh[4][S];
  const int t = threadIdx.x;
  const int lane = t & 63;
  const int wv = t >> 6;
  const int b = blockIdx.x;

  if (b < 256) {
    const int j = b * 4 + wv;
    const float* wrow = attn_w + (size_t)j * (2 * H);
    float4 wlo[4], whi[4], hid4[4];
    #pragma unroll
    for (int q = 0; q < 4; ++q) {
      const int idx = lane + 64 * q;
      wlo[q]  = ((const float4*)wrow)[idx];
      whi[q]  = ((const float4*)(wrow + H))[idx];
      hid4[q] = ((const float4*)hidden)[idx];
    }
    float hp = 0.f;
    #pragma unroll
    for (int q = 0; q < 4; ++q)
      hp += wlo[q].x * hid4[q].x + wlo[q].y * hid4[q].y +
            wlo[q].z * hid4[q].z + wlo[q].w * hid4[q].w;
    hp = wave_reduce_sum(hp);

    float myval = 0.f;
    #pragma unroll
    for (int s = 0; s < S; ++s) {
      const float4* e4 = (const float4*)(enc + s * H);
      float es = 0.f;
      #pragma unroll
      for (int q = 0; q < 4; ++q) {
        const float4 e = e4[lane + 64 * q];
        es += whi[q].x * e.x + whi[q].y * e.y + whi[q].z * e.z + whi[q].w * e.w;
      }
      es = wave_reduce_sum(es);
      if (lane == s) myval = es;
    }
    if (lane < S)
      esh[wv][lane] = tanhf(hp + myval + attn_b[j]) * v_w[j];
    __syncthreads();
    if (wv == 0 && lane < S)
      bpart[lane * 256 + b] =
          esh[0][lane] + esh[1][lane] + esh[2][lane] + esh[3][lane];
  } else if (b < 1024) {
    const int W = (b - 256) * 4 + wv;
    const float* wr = w_ih + (size_t)W * (2 * H);
    const float* embed = embed_table + (size_t)(*token) * H;
    float a = 0.f;
    #pragma unroll
    for (int q = 0; q < 4; ++q) {
      const int idx = lane + 64 * q;
      const float4 w = ((const float4*)wr)[idx];
      const float4 e = ((const float4*)embed)[idx];
      a += w.x * e.x + w.y * e.y + w.z * e.z + w.w * e.w;
    }
    a = wave_reduce_sum(a);
    if (lane == 0) gie[W] = a + b_ih[W];
  } else {
    const int W = (b - 1024) * 4 + wv;
    const float* wr = w_hh + (size_t)W * H;
    float a = 0.f;
    #pragma unroll
    for (int q = 0; q < 4; ++q) {
      const int idx = lane + 64 * q;
      const float4 w = ((const float4*)wr)[idx];
      const float4 h = ((const float4*)hidden)[idx];
      a += w.x * h.x + w.y * h.y + w.z * h.z + w.w * h.w;
    }
    a = wave_reduce_sum(a);
    if (lane == 0) ghv[W] = a + b_hh[W];
  }
}

// ============ kB: redundant softmax+context, 3 ctx rows/wave, gates -> hnew ==
__global__ __launch_bounds__(256) void kB(
    const float* __restrict__ enc,
    const float* __restrict__ bpart,
    const float* __restrict__ w_ih,
    const float* __restrict__ gie,
    const float* __restrict__ ghv,
    const float* __restrict__ hidden,
    float* __restrict__ hnew,
    float* __restrict__ out)      // out[V..V+H) gets hnew
{
  __shared__ float scores_sh[S];
  __shared__ float attn_sh[S];
  __shared__ float wsh[H];
  const int t = threadIdx.x;
  const int lane = t & 63;
  const int wv = t >> 6;
  const int j = blockIdx.x * 4 + wv;

  for (int s = wv; s < S; s += 4) {
    const float4 p = ((const float4*)(bpart + s * 256))[lane];
    float v = wave_reduce_sum(p.x + p.y + p.z + p.w);
    if (lane == 0) scores_sh[s] = v;
  }
  __syncthreads();
  if (t == 0) {
    float m = -1e30f;
    for (int s = 0; s < S; ++s) m = fmaxf(m, scores_sh[s]);
    float sum = 0.f;
    for (int s = 0; s < S; ++s) {
      const float e = expf(scores_sh[s] - m);
      attn_sh[s] = e;
      sum += e;
    }
    const float inv = 1.f / sum;
    for (int s = 0; s < S; ++s) attn_sh[s] *= inv;
  }
  __syncthreads();
  for (int h = t; h < H; h += 256) {
    float acc = 0.f;
    #pragma unroll
    for (int s = 0; s < S; ++s) acc += attn_sh[s] * enc[s * H + h];
    wsh[h] = acc;
  }
  __syncthreads();

  float4 c4[4];
  #pragma unroll
  for (int q = 0; q < 4; ++q) c4[q] = ((const float4*)wsh)[lane + 64 * q];

  float gict[3];
  #pragma unroll
  for (int g = 0; g < 3; ++g) {
    const float* wr = w_ih + (size_t)(g * H + j) * (2 * H) + H;
    float a = 0.f;
    #pragma unroll
    for (int q = 0; q < 4; ++q) {
      const float4 w = ((const float4*)wr)[lane + 64 * q];
      a += w.x * c4[q].x + w.y * c4[q].y + w.z * c4[q].z + w.w * c4[q].w;
    }
    gict[g] = wave_reduce_sum(a);
  }

  if (lane == 0) {
    const float i_r = gie[j]         + gict[0];
    const float i_z = gie[H + j]     + gict[1];
    const float i_n = gie[2 * H + j] + gict[2];
    const float h_r = ghv[j];
    const float h_z = ghv[H + j];
    const float h_n = ghv[2 * H + j];
    const float r = 1.f / (1.f + expf(-(i_r + h_r)));
    const float z = 1.f / (1.f + expf(-(i_z + h_z)));
    const float n = tanhf(i_n + r * h_n);
    const float hn = (1.f - z) * n + z * hidden[j];
    hnew[j] = hn;
    out[V + j] = hn;
  }
}

// ============ kC: balanced-chunk streaming logits + per-block stats ==========
// 512 blocks x 512 threads, 2 blocks/CU. Wave gw owns rows
// [gw*V/4096, (gw+1)*V/4096) -- 12 or 13 rows, 6% max imbalance.
__global__ __launch_bounds__(512, 4) void kC(
    const float* __restrict__ hnew,
    const float* __restrict__ out_w,    // [V][H]
    const float* __restrict__ out_b,    // [V]
    float* __restrict__ out,            // logits
    float* __restrict__ pmax,           // [KC_BLOCKS]
    float* __restrict__ psum)           // [KC_BLOCKS]
{
  __shared__ float stat_m[8];
  __shared__ float stat_s[8];
  const int t = threadIdx.x;
  const int lane = t & 63;
  const int wv = t >> 6;
  const int b = blockIdx.x;
  const long long gw = b * 8 + wv;

  float4 h4[4];
  #pragma unroll
  for (int q = 0; q < 4; ++q)
    h4[q] = ((const float4*)hnew)[lane + 64 * q];

  const int r0 = (int)((gw * V) / KC_WAVES);
  const int r1 = (int)(((gw + 1) * V) / KC_WAVES);

  float wm = -INFINITY, wsum = 0.f;

  int r = r0;
  for (; r + 4 <= r1; r += 4) {
    const float4* p0 = (const float4*)(out_w + (size_t)(r + 0) * H);
    const float4* p1 = (const float4*)(out_w + (size_t)(r + 1) * H);
    const float4* p2 = (const float4*)(out_w + (size_t)(r + 2) * H);
    const float4* p3 = (const float4*)(out_w + (size_t)(r + 3) * H);
    float a0 = 0.f, a1 = 0.f, a2 = 0.f, a3 = 0.f;
    #pragma unroll
    for (int q = 0; q < 4; ++q) {
      const int idx = lane + 64 * q;
      const float4 w0 = p0[idx];
      const float4 w1 = p1[idx];
      const float4 w2 = p2[idx];
      const float4 w3 = p3[idx];
      a0 += w0.x * h4[q].x + w0.y * h4[q].y + w0.z * h4[q].z + w0.w * h4[q].w;
      a1 += w1.x * h4[q].x + w1.y * h4[q].y + w1.z * h4[q].z + w1.w * h4[q].w;
      a2 += w2.x * h4[q].x + w2.y * h4[q].y + w2.z * h4[q].z + w2.w * h4[q].w;
      a3 += w3.x * h4[q].x + w3.y * h4[q].y + w3.z * h4[q].z + w3.w * h4[q].w;
    }
    a0 = wave_reduce_sum(a0);
    a1 = wave_reduce_sum(a1);
    a2 = wave_reduce_sum(a2);
    a3 = wave_reduce_sum(a3);
    const float val0 = a0 + out_b[r + 0];
    const float val1 = a1 + out_b[r + 1];
    const float val2 = a2 + out_b[r + 2];
    const float val3 = a3 + out_b[r + 3];

    // lanes 0-3 store the quad (vals are wave-uniform after reduce)
    const float vv = (lane == 0) ? val0 : (lane == 1) ? val1
                   : (lane == 2) ? val2 : val3;
    if (lane < 4) out[r + lane] = vv;

    const float gm = fmaxf(fmaxf(val0, val1), fmaxf(val2, val3));
    const float M2 = fmaxf(wm, gm);
    wsum = wsum * expf(wm - M2) +
           expf(val0 - M2) + expf(val1 - M2) + expf(val2 - M2) + expf(val3 - M2);
    wm = M2;
  }
  for (; r < r1; ++r) {
    const float4* p0 = (const float4*)(out_w + (size_t)r * H);
    float a0 = 0.f;
    #pragma unroll
    for (int q = 0; q < 4; ++q) {
      const float4 w0 = p0[lane + 64 * q];
      a0 += w0.x * h4[q].x + w0.y * h4[q].y + w0.z * h4[q].z + w0.w * h4[q].w;
    }
    a0 = wave_reduce_sum(a0);
    const float val0 = a0 + out_b[r];
    if (lane == 0) out[r] = val0;
    const float M2 = fmaxf(wm, val0);
    wsum = wsum * expf(wm - M2) + expf(val0 - M2);
    wm = M2;
  }

  if (lane == 0) { stat_m[wv] = wm; stat_s[wv] = wsum; }
  __syncthreads();
  if (t == 0) {
    float M = stat_m[0], Ss = stat_s[0];
    #pragma unroll
    for (int i = 1; i < 8; ++i) {
      const float m2 = stat_m[i], s2 = stat_s[i];
      const float M2 = fmaxf(M, m2);
      Ss = Ss * expf(M - M2) + s2 * expf(m2 - M2);
      M = M2;
    }
    pmax[b] = M;
    psum[b] = Ss;
  }
}

// ============ kD: block-redundant stat reduce + subtract ============
__global__ __launch_bounds__(512) void kD(
    const float* __restrict__ pmax,
    const float* __restrict__ psum,
    float* __restrict__ out)
{
  __shared__ float sm[8];
  __shared__ float ss[8];
  __shared__ float Tsh;
  const int t = threadIdx.x, lane = t & 63, wv = t >> 6;

  float dm = pmax[t];
  float dsv = psum[t];
  #pragma unroll
  for (int off = 32; off > 0; off >>= 1) {
    const float m2 = __shfl_xor(dm, off, 64);
    const float s2 = __shfl_xor(dsv, off, 64);
    const float M2 = fmaxf(dm, m2);
    dsv = dsv * expf(dm - M2) + s2 * expf(m2 - M2);
    dm = M2;
  }
  if (lane == 0) { sm[wv] = dm; ss[wv] = dsv; }
  __syncthreads();
  if (t == 0) {
    float M = sm[0], Ss = ss[0];
    #pragma unroll
    for (int i = 1; i < 8; ++i) {
      const float m2 = sm[i], s2 = ss[i];
      const float M2 = fmaxf(M, m2);
      Ss = Ss * expf(M - M2) + s2 * expf(m2 - M2);
      M = M2;
    }
    Tsh = M + logf(Ss);
  }
  __syncthreads();
  const float T = Tsh;
  const int i = blockIdx.x * 512 + t;
  if (i < V) out[i] -= T;
}

extern "C" void kernel_launch(void* const* d_in, const int* in_sizes, int n_in,
                              void* d_out, int out_size, void* d_ws, size_t ws_size,
                              hipStream_t stream) {
  const int*   token       = (const int*)d_in[0];
  const float* hidden      = (const float*)d_in[1];
  const float* enc         = (const float*)d_in[2];
  const float* embed_table = (const float*)d_in[3];
  const float* attn_w      = (const float*)d_in[4];
  const float* attn_b      = (const float*)d_in[5];
  const float* v_w         = (const float*)d_in[6];
  const float* w_ih        = (const float*)d_in[7];
  const float* w_hh        = (const float*)d_in[8];
  const float* b_ih        = (const float*)d_in[9];
  const float* b_hh        = (const float*)d_in[10];
  const float* out_w       = (const float*)d_in[11];
  const float* out_b       = (const float*)d_in[12];
  float* out = (float*)d_out;
  float* ws  = (float*)d_ws;

  // ws layout (floats)
  float* bpart = ws;           // 5120
  float* gie   = ws + 5120;    // 3072
  float* ghv   = ws + 8192;    // 3072
  float* hnew  = ws + 11264;   // 1024
  float* pmax  = ws + 12288;   // 512
  float* psum  = ws + 12800;   // 512

  kA<<<1792, 256, 0, stream>>>(token, hidden, enc, embed_table, attn_w, attn_b,
                               v_w, w_ih, w_hh, b_ih, b_hh, bpart, gie, ghv);
  kB<<<256, 256, 0, stream>>>(enc, bpart, w_ih, gie, ghv, hidden, hnew, out);
  kC<<<KC_BLOCKS, 512, 0, stream>>>(hnew, out_w, out_b, out, pmax, psum);
  kD<<<(V + 511) / 512, 512, 0, stream>>>(pmax, psum, out);
}